// Round 7
// baseline (269.768 us; speedup 1.0000x reference)
//
#include <hip/hip_runtime.h>
#include <hip/hip_bf16.h>
#include <math.h>

// ---------------- constants ----------------
#define B_    32
#define NCLS_ 20
#define T_    2048
#define D_    2048
#define L_    128
#define NPAIR 16
#define SLICE_STRIDE 524288          // 32*16384 floats between K-slices

typedef __attribute__((ext_vector_type(8))) short bf16x8;
typedef __attribute__((ext_vector_type(4))) float f32x4;

__device__ __forceinline__ ushort f2bf(float f) {
    __hip_bfloat16 h = __float2bfloat16(f);
    return *reinterpret_cast<ushort*>(&h);
}

// lane-shift by 1 (lane l gets lane l-1's value) via DPP wave_shr:1 when available
__device__ __forceinline__ float wave_shr1(float x) {
#if __has_builtin(__builtin_amdgcn_update_dpp)
    int r = __builtin_amdgcn_update_dpp(0, __builtin_bit_cast(int, x),
                                        0x138 /*wave_shr:1*/, 0xf, 0xf, true);
    return __builtin_bit_cast(float, r);
#else
    return __shfl_up(x, 1);
#endif
}
__device__ __forceinline__ float rdlane63(float x) {
#if __has_builtin(__builtin_amdgcn_readlane)
    return __builtin_bit_cast(float,
        __builtin_amdgcn_readlane(__builtin_bit_cast(int, x), 63));
#else
    return __shfl(x, 63);
#endif
}

// ---------------- fused row-norm + guide/sparse kernel ----------------
// blocks 0..4095: lcs rows; 4096..20479: fsd halves; 20480..20575: feat rows;
// 20576..21599: guide/sparse (64 elems each)
__global__ __launch_bounds__(64) void norm_guide_kernel(
        const float* __restrict__ lcs, const float* __restrict__ fa,
        const float* __restrict__ fb, const float* __restrict__ fi,
        const float* __restrict__ fc, const float* __restrict__ fbk,
        const float* __restrict__ att, const float* __restrict__ cas,
        float* __restrict__ rn, float* __restrict__ nfeat,
        float* __restrict__ acc) {
    __shared__ float sc[64 * 21 + 64 * 3];
    int b = blockIdx.x;
    int tid = threadIdx.x;

    if (b >= 20576) {
        float* sa = sc + 64 * 21;
        size_t e0 = (size_t)(b - 20576) * 64;
        const float4* pc = (const float4*)(cas + e0 * 21);
        #pragma unroll
        for (int i = 0; i < 6; ++i) {
            int idx = tid + i * 64;
            if (idx < 336) *(float4*)&sc[idx * 4] = pc[idx];
        }
        const float4* pa = (const float4*)(att + e0 * 3);
        if (tid < 48) *(float4*)&sa[tid * 4] = pa[tid];
        __syncthreads();
        float a0 = sa[tid * 3], a1 = sa[tid * 3 + 1];
        float g = fabsf(1.f - sc[tid * 21 + 20] - a0);
        float sp = a0 + a1;
        #pragma unroll
        for (int off = 32; off; off >>= 1) {
            g += __shfl_down(g, off);
            sp += __shfl_down(sp, off);
        }
        if (tid == 0) {
            atomicAdd(&acc[0], g);
            atomicAdd(&acc[1], sp);
        }
        return;
    }

    const float* src; float* dst; int len4; int recip = 1;
    if (b < 4096) {
        src = lcs + (size_t)b * 2048; dst = rn + b; len4 = 512;
    } else if (b < 20480) {
        int region = (b - 4096) >> 12;
        int r = (b - 4096) & 4095;
        const float* base = (region < 2) ? fa : fb;
        src = base + (size_t)r * 2048 + (region & 1) * 1024;
        dst = rn + b; len4 = 256;
    } else {
        int r = b - 20480;
        const float* base = (r < 32) ? fi : (r < 64 ? fc : fbk);
        src = base + (size_t)(r & 31) * 2048;
        dst = nfeat + r; len4 = 512; recip = 0;
    }
    const float4* p = (const float4*)src;
    float s = 0.f;
    for (int i = tid; i < len4; i += 64) {
        float4 v = p[i];
        s += v.x * v.x + v.y * v.y + v.z * v.z + v.w * v.w;
    }
    #pragma unroll
    for (int off = 32; off; off >>= 1) s += __shfl_down(s, off);
    if (tid == 0) *dst = recip ? rsqrtf(s) : sqrtf(s);
}

// ---------------- MFMA similarity kernel (runtime K-split, raw partials) ----
// grid = 32*sl + 64*sf blocks.
__global__ __launch_bounds__(256) void sim_mfma_kernel(
        const float* __restrict__ lcs, const float* __restrict__ fa,
        const float* __restrict__ fb, const int* __restrict__ pos,
        const int* __restrict__ neg, float* __restrict__ lcs_part,
        float* __restrict__ m_part, float* __restrict__ g_part,
        int sl, int sf) {
    int bid = blockIdx.x;
    const float *Aptr, *Bptr;
    float* out;
    int nst;

    if (bid < 32 * sl) {
        int job = bid / sl, ks = bid - job * sl;
        int kofs = ks * (2048 / sl);
        nst = 2048 / (64 * sl);
        int pi = job & 15;
        const int* pp = (job >= 16) ? neg : pos;
        int p0 = pp[2 * pi], p1 = pp[2 * pi + 1];
        Aptr = lcs + (size_t)p0 * L_ * D_ + kofs;
        Bptr = lcs + (size_t)p1 * L_ * D_ + kofs;
        out = lcs_part + ((size_t)ks * 32 + job) * 16384;
    } else {
        int e = bid - 32 * sl;
        int fj = e / sf, ks = e - fj * sf;
        int kofs = ks * (1024 / sf);
        nst = 1024 / (64 * sf);
        int isneg = fj >= 32;
        int q = fj & 31;
        int pi = q >> 1, half = q & 1;
        const int* pp = isneg ? neg : pos;
        int p0 = pp[2 * pi], p1 = pp[2 * pi + 1];
        const float* Bbase = isneg ? fb : fa;
        Aptr = fa + (size_t)p0 * L_ * D_ + half * 1024 + kofs;
        Bptr = Bbase + (size_t)p1 * L_ * D_ + half * 1024 + kofs;
        int slot = (isneg ? 16 : 0) + pi;
        out = (half ? g_part : m_part) + ((size_t)ks * 32 + slot) * 16384;
    }

    __shared__ ushort lA[2][128 * 64];
    __shared__ ushort lB[2][128 * 64];
    int tid = threadIdx.x;
    int lane = tid & 63;
    int w = tid >> 6;
    int wr = w >> 1, wc = w & 1;
    int lrow = lane & 15, lhk = lane >> 4;

    int srow[4], skb[4];
    #pragma unroll
    for (int i = 0; i < 4; ++i) {
        int c = tid + i * 256;
        srow[i] = c >> 3; skb[i] = c & 7;
    }

    float4 pa0[4], pa1[4], pb0[4], pb1[4];

    f32x4 acc[4][4];
    #pragma unroll
    for (int m = 0; m < 4; ++m)
        #pragma unroll
        for (int n = 0; n < 4; ++n)
            acc[m][n] = (f32x4){0.f, 0.f, 0.f, 0.f};

    #pragma unroll
    for (int i = 0; i < 4; ++i) {
        const float* sA = Aptr + (size_t)srow[i] * D_ + skb[i] * 8;
        pa0[i] = *(const float4*)sA; pa1[i] = *(const float4*)(sA + 4);
        const float* sB = Bptr + (size_t)srow[i] * D_ + skb[i] * 8;
        pb0[i] = *(const float4*)sB; pb1[i] = *(const float4*)(sB + 4);
    }
    #pragma unroll
    for (int i = 0; i < 4; ++i) {
        int idx = ((srow[i] * 64 + skb[i] * 8) ^ ((srow[i] & 7) << 3));
        bf16x8 sv, sw;
        sv[0] = (short)f2bf(pa0[i].x); sv[1] = (short)f2bf(pa0[i].y);
        sv[2] = (short)f2bf(pa0[i].z); sv[3] = (short)f2bf(pa0[i].w);
        sv[4] = (short)f2bf(pa1[i].x); sv[5] = (short)f2bf(pa1[i].y);
        sv[6] = (short)f2bf(pa1[i].z); sv[7] = (short)f2bf(pa1[i].w);
        *(bf16x8*)&lA[0][idx] = sv;
        sw[0] = (short)f2bf(pb0[i].x); sw[1] = (short)f2bf(pb0[i].y);
        sw[2] = (short)f2bf(pb0[i].z); sw[3] = (short)f2bf(pb0[i].w);
        sw[4] = (short)f2bf(pb1[i].x); sw[5] = (short)f2bf(pb1[i].y);
        sw[6] = (short)f2bf(pb1[i].z); sw[7] = (short)f2bf(pb1[i].w);
        *(bf16x8*)&lB[0][idx] = sw;
    }
    __syncthreads();

    for (int t = 0; t < nst; ++t) {
        if (t < nst - 1) {
            int k0 = (t + 1) * 64;
            #pragma unroll
            for (int i = 0; i < 4; ++i) {
                const float* sA = Aptr + (size_t)srow[i] * D_ + k0 + skb[i] * 8;
                pa0[i] = *(const float4*)sA; pa1[i] = *(const float4*)(sA + 4);
                const float* sB = Bptr + (size_t)srow[i] * D_ + k0 + skb[i] * 8;
                pb0[i] = *(const float4*)sB; pb1[i] = *(const float4*)(sB + 4);
            }
        }
        #pragma unroll
        for (int ks = 0; ks < 2; ++ks) {
            int kbase = ks * 32 + lhk * 8;
            bf16x8 afr[4], bfr[4];
            #pragma unroll
            for (int m = 0; m < 4; ++m) {
                int row = wr * 64 + m * 16 + lrow;
                int idx = ((row * 64 + kbase) ^ ((row & 7) << 3));
                afr[m] = *(const bf16x8*)&lA[t & 1][idx];
            }
            #pragma unroll
            for (int n = 0; n < 4; ++n) {
                int row = wc * 64 + n * 16 + lrow;
                int idx = ((row * 64 + kbase) ^ ((row & 7) << 3));
                bfr[n] = *(const bf16x8*)&lB[t & 1][idx];
            }
            #pragma unroll
            for (int m = 0; m < 4; ++m)
                #pragma unroll
                for (int n = 0; n < 4; ++n)
                    acc[m][n] = __builtin_amdgcn_mfma_f32_16x16x32_bf16(
                        afr[m], bfr[n], acc[m][n], 0, 0, 0);
        }
        if (t < nst - 1) {
            #pragma unroll
            for (int i = 0; i < 4; ++i) {
                int idx = ((srow[i] * 64 + skb[i] * 8) ^ ((srow[i] & 7) << 3));
                bf16x8 sv, sw;
                sv[0] = (short)f2bf(pa0[i].x); sv[1] = (short)f2bf(pa0[i].y);
                sv[2] = (short)f2bf(pa0[i].z); sv[3] = (short)f2bf(pa0[i].w);
                sv[4] = (short)f2bf(pa1[i].x); sv[5] = (short)f2bf(pa1[i].y);
                sv[6] = (short)f2bf(pa1[i].z); sv[7] = (short)f2bf(pa1[i].w);
                *(bf16x8*)&lA[(t + 1) & 1][idx] = sv;
                sw[0] = (short)f2bf(pb0[i].x); sw[1] = (short)f2bf(pb0[i].y);
                sw[2] = (short)f2bf(pb0[i].z); sw[3] = (short)f2bf(pb0[i].w);
                sw[4] = (short)f2bf(pb1[i].x); sw[5] = (short)f2bf(pb1[i].y);
                sw[6] = (short)f2bf(pb1[i].z); sw[7] = (short)f2bf(pb1[i].w);
                *(bf16x8*)&lB[(t + 1) & 1][idx] = sw;
            }
        }
        __syncthreads();
    }

    #pragma unroll
    for (int m = 0; m < 4; ++m) {
        #pragma unroll
        for (int n = 0; n < 4; ++n) {
            int jj = wc * 64 + n * 16 + lrow;
            #pragma unroll
            for (int r = 0; r < 4; ++r) {
                int ii = wr * 64 + m * 16 + lhk * 4 + r;
                out[ii * L_ + jj] = acc[m][n][r];
            }
        }
    }
}

// ---------------- fused reduce+DP kernel ----------------
// 64 blocks x 256 threads. blocks 0..31 LCS, 32..63 FSD.
__global__ __launch_bounds__(256) void dp_kernel(
        const int* __restrict__ pos, const int* __restrict__ neg,
        const float* __restrict__ lcs_part, const float* __restrict__ m_part,
        const float* __restrict__ g_part, const float* __restrict__ rn,
        float* __restrict__ lres, float* __restrict__ fres,
        int sl, int sf) {
    __shared__ float Sm[128 * 128];
    __shared__ float Sg[128 * 128];
    int job = blockIdx.x;
    int tid = threadIdx.x;
    bool is_lcs = job < 32;

    if (is_lcs) {
        int pi = job & 15;
        const int* pp = (job >= 16) ? neg : pos;
        int p0 = pp[2 * pi], p1 = pp[2 * pi + 1];
        const float* P = lcs_part + (size_t)job * 16384;
        const float* rA = rn + p0 * 128;
        const float* rB = rn + p1 * 128;
        for (int c = 0; c < 16; ++c) {
            int base = (c * 256 + tid) * 4;
            int r = base >> 7, j0 = base & 127;
            float4 sacc = {0.f, 0.f, 0.f, 0.f};
            for (int s = 0; s < sl; ++s) {
                float4 v = *(const float4*)&P[(size_t)s * SLICE_STRIDE + base];
                sacc.x += v.x; sacc.y += v.y; sacc.z += v.z; sacc.w += v.w;
            }
            float ra = rA[r];
            float4 rb = *(const float4*)&rB[j0];
            float4 sv;
            sv.x = fmaxf((sacc.x * ra * rb.x - 0.8f) * 5.f, 0.f);
            sv.y = fmaxf((sacc.y * ra * rb.y - 0.8f) * 5.f, 0.f);
            sv.z = fmaxf((sacc.z * ra * rb.z - 0.8f) * 5.f, 0.f);
            sv.w = fmaxf((sacc.w * ra * rb.w - 0.8f) * 5.f, 0.f);
            *(float4*)&Sm[base] = sv;
        }
    } else {
        int fj = job - 32;
        int isneg = fj >= 16;
        int pi = fj & 15;
        const int* pp = isneg ? neg : pos;
        int p0 = pp[2 * pi], p1 = pp[2 * pi + 1];
        const float* Pm = m_part + (size_t)fj * 16384;
        const float* Pg = g_part + (size_t)fj * 16384;
        const float* rAm = rn + 4096 + p0 * 128;
        const float* rBm = rn + (isneg ? 12288 : 4096) + p1 * 128;
        const float* rAg = rn + 8192 + p0 * 128;
        const float* rBg = rn + (isneg ? 16384 : 8192) + p1 * 128;
        for (int c = 0; c < 16; ++c) {
            int base = (c * 256 + tid) * 4;
            int r = base >> 7, j0 = base & 127;
            float4 macc = {0.f, 0.f, 0.f, 0.f}, gacc = {0.f, 0.f, 0.f, 0.f};
            for (int s = 0; s < sf; ++s) {
                float4 m = *(const float4*)&Pm[(size_t)s * SLICE_STRIDE + base];
                float4 g = *(const float4*)&Pg[(size_t)s * SLICE_STRIDE + base];
                macc.x += m.x; macc.y += m.y; macc.z += m.z; macc.w += m.w;
                gacc.x += g.x; gacc.y += g.y; gacc.z += g.z; gacc.w += g.w;
            }
            float ram = rAm[r], rag = rAg[r];
            float4 rbm = *(const float4*)&rBm[j0];
            float4 rbg = *(const float4*)&rBg[j0];
            float4 mv, gv;
            mv.x = macc.x * ram * rbm.x; mv.y = macc.y * ram * rbm.y;
            mv.z = macc.z * ram * rbm.z; mv.w = macc.w * ram * rbm.w;
            gv.x = gacc.x * rag * rbg.x; gv.y = gacc.y * rag * rbg.y;
            gv.z = gacc.z * rag * rbg.z; gv.w = gacc.w * rag * rbg.w;
            *(float4*)&Sm[base] = mv;
            *(float4*)&Sg[base] = gv;
        }
    }
    __syncthreads();

    if (tid >= 64) return;
    int l = tid;
    const float* SA = Sm + l * 128;            // row l
    const float* SB = Sm + (64 + l) * 128;     // row 64+l
    float a = 0.f, b = 0.f, ua_prev = 0.f, ub_prev = 0.f;

    if (is_lcs) {
        float sa_buf[8], sb_buf[8];
        #pragma unroll
        for (int p = 0; p < 8; ++p) {
            sa_buf[p] = SA[min(max(p - l, 0), 127)];
            sb_buf[p] = SB[min(max(p - 64 - l, 0), 127)];
        }
        #pragma unroll 8
        for (int t = 0; t < 256; ++t) {
            int slot = t & 7;
            float sa = sa_buf[slot], sb = sb_buf[slot];
            float ua = wave_shr1(a);
            float ub = wave_shr1(b);
            float a63 = rdlane63(a);
            if (l == 0) { ua = 0.f; ub = a63; }
            int ja = t - l, jb = t - 64 - l;
            float newa = (sa > 0.5f) ? (ua_prev + sa) : fmaxf(ua, a);
            float newb = (sb > 0.5f) ? (ub_prev + sb) : fmaxf(ub, b);
            if (ja >= 0 && ja < 128) a = newa;
            if (jb >= 0 && jb < 128) b = newb;
            ua_prev = ua; ub_prev = ub;
            sa_buf[slot] = SA[min(max(t + 8 - l, 0), 127)];
            sb_buf[slot] = SB[min(max(t + 8 - 64 - l, 0), 127)];
        }
        if (l == 63) lres[job] = b;
    } else {
        const float* GA = Sg + l * 128;
        const float* GB = Sg + (64 + l) * 128;
        float mab[8], gab[8], mbb[8], gbb[8];
        #pragma unroll
        for (int p = 0; p < 8; ++p) {
            int ja = min(max(p - l, 0), 127), jb = min(max(p - 64 - l, 0), 127);
            mab[p] = SA[ja]; gab[p] = GA[ja];
            mbb[p] = SB[jb]; gbb[p] = GB[jb];
        }
        #pragma unroll 8
        for (int t = 0; t < 256; ++t) {
            int slot = t & 7;
            float ma = mab[slot], ga = gab[slot], mb = mbb[slot], gb = gbb[slot];
            float ua = wave_shr1(a);
            float ub = wave_shr1(b);
            float a63 = rdlane63(a);
            if (l == 0) { ua = 0.f; ub = a63; }
            int ja = t - l, jb = t - 64 - l;
            float x0 = ua_prev, x1 = ga + ua, x2 = ga + a;
            float mx = fmaxf(x0, fmaxf(x1, x2));
            float e0 = __expf((x0 - mx) * 10.f);
            float e1 = __expf((x1 - mx) * 10.f);
            float e2 = __expf((x2 - mx) * 10.f);
            float newa = ma + mx + 0.1f * __logf(e0 + e1 + e2);
            float y0 = ub_prev, y1 = gb + ub, y2 = gb + b;
            float my = fmaxf(y0, fmaxf(y1, y2));
            float f0 = __expf((y0 - my) * 10.f);
            float f1 = __expf((y1 - my) * 10.f);
            float f2 = __expf((y2 - my) * 10.f);
            float newb = mb + my + 0.1f * __logf(f0 + f1 + f2);
            if (ja >= 0 && ja < 128) a = newa;
            if (jb >= 0 && jb < 128) b = newb;
            ua_prev = ua; ub_prev = ub;
            int jan = min(max(t + 8 - l, 0), 127), jbn = min(max(t + 8 - 64 - l, 0), 127);
            mab[slot] = SA[jan]; gab[slot] = GA[jan];
            mbb[slot] = SB[jbn]; gbb[slot] = GB[jbn];
        }
        if (l == 63) fres[job - 32] = b;
    }
}

// ---------------- final combine (1 block, 64 threads) ----------------
__global__ __launch_bounds__(64) void final_kernel(
        const float* __restrict__ xi, const float* __restrict__ xc,
        const float* __restrict__ xb, const float* __restrict__ vl,
        const float* __restrict__ nfeat, const float* __restrict__ lcs_res,
        const float* __restrict__ fsd_res, const float* __restrict__ acc,
        float* __restrict__ out) {
    int lane = threadIdx.x;
    float part = 0.f;

    if (lane < B_) {
        int b = lane;
        float sv = 0.f;
        for (int j = 0; j < NCLS_; ++j) sv += vl[b * NCLS_ + j];
        float inv_i = 1.f / sv;
        float inv_c = 1.f / (sv + 1.f);
        float si = 0.f, sc = 0.f;
        for (int j = 0; j < NCLS_; ++j) {
            float lab = vl[b * NCLS_ + j];
            if (lab != 0.f) {
                si += logf(xi[b * (NCLS_ + 1) + j] + 1e-45f) * lab * inv_i;
                sc += logf(xc[b * (NCLS_ + 1) + j] + 1e-45f) * lab * inv_c;
            }
        }
        sc += logf(xc[b * (NCLS_ + 1) + NCLS_] + 1e-45f) * inv_c;
        float sb = logf(xb[b * (NCLS_ + 1) + NCLS_] + 1e-45f);
        float cls = -(si + sc + sb) / (float)B_;

        float ni = nfeat[b], nc = nfeat[B_ + b], nb = nfeat[2 * B_ + b];
        float f1 = fmaxf(50.f - ni + nc, 0.f);
        float f2 = fmaxf(50.f - nc + nb, 0.f);
        float fv = f1 + f2 + nb;
        float feat = fv * fv / (float)B_;

        float sgn = (b < NPAIR) ? -1.f : 1.f;
        float lcs = sgn * lcs_res[b] / (float)NPAIR;
        float fsd = sgn * fsd_res[b] / (float)NPAIR;

        part = cls + 5e-5f * feat + 0.1f * (lcs + fsd);
    }
    #pragma unroll
    for (int off = 32; off; off >>= 1) part += __shfl_down(part, off);
    if (lane == 0) {
        float guide = acc[0] / (float)B_;
        float sparse = acc[1] / (float)B_;
        out[0] = part + guide + 2e-4f * sparse;
    }
}

// ---------------- launcher ----------------
extern "C" void kernel_launch(void* const* d_in, const int* in_sizes, int n_in,
                              void* d_out, int out_size, void* d_ws, size_t ws_size,
                              hipStream_t stream) {
    const float* act_inst_cls = (const float*)d_in[0];
    const float* act_cont_cls = (const float*)d_in[1];
    const float* act_back_cls = (const float*)d_in[2];
    const float* vid_label    = (const float*)d_in[3];
    const float* temp_att     = (const float*)d_in[4];
    const float* act_inst_feat= (const float*)d_in[5];
    const float* act_cont_feat= (const float*)d_in[6];
    const float* act_back_feat= (const float*)d_in[7];
    const float* temp_cas     = (const float*)d_in[8];
    const float* lcs_candi    = (const float*)d_in[9];
    const float* fsd_act      = (const float*)d_in[10];
    const float* fsd_bak      = (const float*)d_in[11];
    const int*   pos_pair     = (const int*)d_in[12];
    const int*   neg_pair     = (const int*)d_in[13];

    float* ws = (float*)d_ws;
    float* out = (float*)d_out;

    // choose K-split per available workspace:
    //   big:  sl=8, sf=4 -> partials 16*524288 floats = 33.6 MB
    //   small: sl=4, sf=2 -> partials 8*524288 floats = 16.8 MB
    int sl, sf;
    size_t part_floats;
    if (ws_size >= (size_t)36 * 1024 * 1024) {
        sl = 8; sf = 4;
    } else {
        sl = 4; sf = 2;
    }
    part_floats = (size_t)(sl + 2 * sf) * SLICE_STRIDE;

    float* lcs_part = ws;
    float* m_part   = ws + (size_t)sl * SLICE_STRIDE;
    float* g_part   = m_part + (size_t)sf * SLICE_STRIDE;
    float* rn       = ws + part_floats;
    float* nfeat    = rn + 20480;
    float* lres     = nfeat + 96;
    float* fres     = lres + 32;
    float* acc      = fres + 32;

    hipMemsetAsync(acc, 0, 2 * sizeof(float), stream);

    hipLaunchKernelGGL(sim_mfma_kernel, dim3(32 * sl + 64 * sf), dim3(256), 0, stream,
                       lcs_candi, fsd_act, fsd_bak, pos_pair, neg_pair,
                       lcs_part, m_part, g_part, sl, sf);

    hipLaunchKernelGGL(norm_guide_kernel, dim3(21600), dim3(64), 0, stream,
                       lcs_candi, fsd_act, fsd_bak,
                       act_inst_feat, act_cont_feat, act_back_feat,
                       temp_att, temp_cas, rn, nfeat, acc);

    hipLaunchKernelGGL(dp_kernel, dim3(64), dim3(256), 0, stream,
                       pos_pair, neg_pair, lcs_part, m_part, g_part, rn,
                       lres, fres, sl, sf);

    hipLaunchKernelGGL(final_kernel, dim3(1), dim3(64), 0, stream,
                       act_inst_cls, act_cont_cls, act_back_cls, vid_label,
                       nfeat, lres, fres, acc, out);
}

// Round 8
// 261.256 us; speedup vs baseline: 1.0326x; 1.0326x over previous
//
#include <hip/hip_runtime.h>
#include <hip/hip_bf16.h>
#include <math.h>

// ---------------- constants ----------------
#define B_    32
#define NCLS_ 20
#define T_    2048
#define D_    2048
#define L_    128
#define NPAIR 16
#define SL    8                      // LCS K-slices (compile-time!)
#define SF    4                      // FSD K-slices (compile-time!)
#define SLICE_STRIDE 524288          // 32*16384 floats between K-slices

typedef __attribute__((ext_vector_type(8))) short bf16x8;
typedef __attribute__((ext_vector_type(4))) float f32x4;

__device__ __forceinline__ ushort f2bf(float f) {
    __hip_bfloat16 h = __float2bfloat16(f);
    return *reinterpret_cast<ushort*>(&h);
}

// lane-shift by 1 (lane l gets lane l-1's value) via DPP wave_shr:1 when available
__device__ __forceinline__ float wave_shr1(float x) {
#if __has_builtin(__builtin_amdgcn_update_dpp)
    int r = __builtin_amdgcn_update_dpp(0, __builtin_bit_cast(int, x),
                                        0x138 /*wave_shr:1*/, 0xf, 0xf, true);
    return __builtin_bit_cast(float, r);
#else
    return __shfl_up(x, 1);
#endif
}
__device__ __forceinline__ float rdlane63(float x) {
#if __has_builtin(__builtin_amdgcn_readlane)
    return __builtin_bit_cast(float,
        __builtin_amdgcn_readlane(__builtin_bit_cast(int, x), 63));
#else
    return __shfl(x, 63);
#endif
}

// ---------------- fused row-norm + guide/sparse kernel ----------------
// blocks 0..4095: lcs rows; 4096..20479: fsd halves; 20480..20575: feat rows;
// 20576..21599: guide/sparse (64 elems each)
__global__ __launch_bounds__(64) void norm_guide_kernel(
        const float* __restrict__ lcs, const float* __restrict__ fa,
        const float* __restrict__ fb, const float* __restrict__ fi,
        const float* __restrict__ fc, const float* __restrict__ fbk,
        const float* __restrict__ att, const float* __restrict__ cas,
        float* __restrict__ rn, float* __restrict__ nfeat,
        float* __restrict__ acc) {
    __shared__ float sc[64 * 21 + 64 * 3];
    int b = blockIdx.x;
    int tid = threadIdx.x;

    if (b >= 20576) {
        float* sa = sc + 64 * 21;
        size_t e0 = (size_t)(b - 20576) * 64;
        const float4* pc = (const float4*)(cas + e0 * 21);
        #pragma unroll
        for (int i = 0; i < 6; ++i) {
            int idx = tid + i * 64;
            if (idx < 336) *(float4*)&sc[idx * 4] = pc[idx];
        }
        const float4* pa = (const float4*)(att + e0 * 3);
        if (tid < 48) *(float4*)&sa[tid * 4] = pa[tid];
        __syncthreads();
        float a0 = sa[tid * 3], a1 = sa[tid * 3 + 1];
        float g = fabsf(1.f - sc[tid * 21 + 20] - a0);
        float sp = a0 + a1;
        #pragma unroll
        for (int off = 32; off; off >>= 1) {
            g += __shfl_down(g, off);
            sp += __shfl_down(sp, off);
        }
        if (tid == 0) {
            atomicAdd(&acc[0], g);
            atomicAdd(&acc[1], sp);
        }
        return;
    }

    const float* src; float* dst; int len4; int recip = 1;
    if (b < 4096) {
        src = lcs + (size_t)b * 2048; dst = rn + b; len4 = 512;
    } else if (b < 20480) {
        int region = (b - 4096) >> 12;
        int r = (b - 4096) & 4095;
        const float* base = (region < 2) ? fa : fb;
        src = base + (size_t)r * 2048 + (region & 1) * 1024;
        dst = rn + b; len4 = 256;
    } else {
        int r = b - 20480;
        const float* base = (r < 32) ? fi : (r < 64 ? fc : fbk);
        src = base + (size_t)(r & 31) * 2048;
        dst = nfeat + r; len4 = 512; recip = 0;
    }
    const float4* p = (const float4*)src;
    float s = 0.f;
    for (int i = tid; i < len4; i += 64) {
        float4 v = p[i];
        s += v.x * v.x + v.y * v.y + v.z * v.z + v.w * v.w;
    }
    #pragma unroll
    for (int off = 32; off; off >>= 1) s += __shfl_down(s, off);
    if (tid == 0) *dst = recip ? rsqrtf(s) : sqrtf(s);
}

// ---------------- MFMA similarity kernel (compile-time K-split) ----------
// grid = 32*SL + 64*SF = 512 blocks, nst = 4 everywhere.
__global__ __launch_bounds__(256) void sim_mfma_kernel(
        const float* __restrict__ lcs, const float* __restrict__ fa,
        const float* __restrict__ fb, const int* __restrict__ pos,
        const int* __restrict__ neg, float* __restrict__ lcs_part,
        float* __restrict__ m_part, float* __restrict__ g_part,
        float* __restrict__ acc) {
    int bid = blockIdx.x;
    // fold the acc zeroing into this (first) kernel: saves a dispatch
    if (bid == 0 && threadIdx.x == 0) { acc[0] = 0.f; acc[1] = 0.f; }

    const float *Aptr, *Bptr;
    float* out;

    if (bid < 32 * SL) {
        int job = bid >> 3, ks = bid & (SL - 1);
        int kofs = ks * (2048 / SL);
        int pi = job & 15;
        const int* pp = (job >= 16) ? neg : pos;
        int p0 = pp[2 * pi], p1 = pp[2 * pi + 1];
        Aptr = lcs + (size_t)p0 * L_ * D_ + kofs;
        Bptr = lcs + (size_t)p1 * L_ * D_ + kofs;
        out = lcs_part + ((size_t)ks * 32 + job) * 16384;
    } else {
        int e = bid - 32 * SL;
        int fj = e >> 2, ks = e & (SF - 1);
        int kofs = ks * (1024 / SF);
        int isneg = fj >= 32;
        int q = fj & 31;
        int pi = q >> 1, half = q & 1;
        const int* pp = isneg ? neg : pos;
        int p0 = pp[2 * pi], p1 = pp[2 * pi + 1];
        const float* Bbase = isneg ? fb : fa;
        Aptr = fa + (size_t)p0 * L_ * D_ + half * 1024 + kofs;
        Bptr = Bbase + (size_t)p1 * L_ * D_ + half * 1024 + kofs;
        int slot = (isneg ? 16 : 0) + pi;
        out = (half ? g_part : m_part) + ((size_t)ks * 32 + slot) * 16384;
    }

    __shared__ ushort lA[2][128 * 64];
    __shared__ ushort lB[2][128 * 64];
    int tid = threadIdx.x;
    int lane = tid & 63;
    int w = tid >> 6;
    int wr = w >> 1, wc = w & 1;
    int lrow = lane & 15, lhk = lane >> 4;

    int srow[4], skb[4];
    #pragma unroll
    for (int i = 0; i < 4; ++i) {
        int c = tid + i * 256;
        srow[i] = c >> 3; skb[i] = c & 7;
    }

    float4 pa0[4], pa1[4], pb0[4], pb1[4];

    f32x4 acc4[4][4];
    #pragma unroll
    for (int m = 0; m < 4; ++m)
        #pragma unroll
        for (int n = 0; n < 4; ++n)
            acc4[m][n] = (f32x4){0.f, 0.f, 0.f, 0.f};

    #pragma unroll
    for (int i = 0; i < 4; ++i) {
        const float* sA = Aptr + (size_t)srow[i] * D_ + skb[i] * 8;
        pa0[i] = *(const float4*)sA; pa1[i] = *(const float4*)(sA + 4);
        const float* sB = Bptr + (size_t)srow[i] * D_ + skb[i] * 8;
        pb0[i] = *(const float4*)sB; pb1[i] = *(const float4*)(sB + 4);
    }
    #pragma unroll
    for (int i = 0; i < 4; ++i) {
        int idx = ((srow[i] * 64 + skb[i] * 8) ^ ((srow[i] & 7) << 3));
        bf16x8 sv, sw;
        sv[0] = (short)f2bf(pa0[i].x); sv[1] = (short)f2bf(pa0[i].y);
        sv[2] = (short)f2bf(pa0[i].z); sv[3] = (short)f2bf(pa0[i].w);
        sv[4] = (short)f2bf(pa1[i].x); sv[5] = (short)f2bf(pa1[i].y);
        sv[6] = (short)f2bf(pa1[i].z); sv[7] = (short)f2bf(pa1[i].w);
        *(bf16x8*)&lA[0][idx] = sv;
        sw[0] = (short)f2bf(pb0[i].x); sw[1] = (short)f2bf(pb0[i].y);
        sw[2] = (short)f2bf(pb0[i].z); sw[3] = (short)f2bf(pb0[i].w);
        sw[4] = (short)f2bf(pb1[i].x); sw[5] = (short)f2bf(pb1[i].y);
        sw[6] = (short)f2bf(pb1[i].z); sw[7] = (short)f2bf(pb1[i].w);
        *(bf16x8*)&lB[0][idx] = sw;
    }
    __syncthreads();

    #pragma unroll
    for (int t = 0; t < 4; ++t) {
        if (t < 3) {
            int k0 = (t + 1) * 64;
            #pragma unroll
            for (int i = 0; i < 4; ++i) {
                const float* sA = Aptr + (size_t)srow[i] * D_ + k0 + skb[i] * 8;
                pa0[i] = *(const float4*)sA; pa1[i] = *(const float4*)(sA + 4);
                const float* sB = Bptr + (size_t)srow[i] * D_ + k0 + skb[i] * 8;
                pb0[i] = *(const float4*)sB; pb1[i] = *(const float4*)(sB + 4);
            }
        }
        #pragma unroll
        for (int ks = 0; ks < 2; ++ks) {
            int kbase = ks * 32 + lhk * 8;
            bf16x8 afr[4], bfr[4];
            #pragma unroll
            for (int m = 0; m < 4; ++m) {
                int row = wr * 64 + m * 16 + lrow;
                int idx = ((row * 64 + kbase) ^ ((row & 7) << 3));
                afr[m] = *(const bf16x8*)&lA[t & 1][idx];
            }
            #pragma unroll
            for (int n = 0; n < 4; ++n) {
                int row = wc * 64 + n * 16 + lrow;
                int idx = ((row * 64 + kbase) ^ ((row & 7) << 3));
                bfr[n] = *(const bf16x8*)&lB[t & 1][idx];
            }
            #pragma unroll
            for (int m = 0; m < 4; ++m)
                #pragma unroll
                for (int n = 0; n < 4; ++n)
                    acc4[m][n] = __builtin_amdgcn_mfma_f32_16x16x32_bf16(
                        afr[m], bfr[n], acc4[m][n], 0, 0, 0);
        }
        if (t < 3) {
            #pragma unroll
            for (int i = 0; i < 4; ++i) {
                int idx = ((srow[i] * 64 + skb[i] * 8) ^ ((srow[i] & 7) << 3));
                bf16x8 sv, sw;
                sv[0] = (short)f2bf(pa0[i].x); sv[1] = (short)f2bf(pa0[i].y);
                sv[2] = (short)f2bf(pa0[i].z); sv[3] = (short)f2bf(pa0[i].w);
                sv[4] = (short)f2bf(pa1[i].x); sv[5] = (short)f2bf(pa1[i].y);
                sv[6] = (short)f2bf(pa1[i].z); sv[7] = (short)f2bf(pa1[i].w);
                *(bf16x8*)&lA[(t + 1) & 1][idx] = sv;
                sw[0] = (short)f2bf(pb0[i].x); sw[1] = (short)f2bf(pb0[i].y);
                sw[2] = (short)f2bf(pb0[i].z); sw[3] = (short)f2bf(pb0[i].w);
                sw[4] = (short)f2bf(pb1[i].x); sw[5] = (short)f2bf(pb1[i].y);
                sw[6] = (short)f2bf(pb1[i].z); sw[7] = (short)f2bf(pb1[i].w);
                *(bf16x8*)&lB[(t + 1) & 1][idx] = sw;
            }
        }
        __syncthreads();
    }

    #pragma unroll
    for (int m = 0; m < 4; ++m) {
        #pragma unroll
        for (int n = 0; n < 4; ++n) {
            int jj = wc * 64 + n * 16 + lrow;
            #pragma unroll
            for (int r = 0; r < 4; ++r) {
                int ii = wr * 64 + m * 16 + lhk * 4 + r;
                out[ii * L_ + jj] = acc4[m][n][r];
            }
        }
    }
}

// ---------------- fused reduce+DP kernel ----------------
// 64 blocks x 256 threads. blocks 0..31 LCS, 32..63 FSD.
// phase 1: COMPILE-TIME unrolled slice reduce -> independent loads in flight.
__global__ __launch_bounds__(256) void dp_kernel(
        const int* __restrict__ pos, const int* __restrict__ neg,
        const float* __restrict__ lcs_part, const float* __restrict__ m_part,
        const float* __restrict__ g_part, const float* __restrict__ rn,
        float* __restrict__ lres, float* __restrict__ fres) {
    __shared__ float Sm[128 * 128];
    __shared__ float Sg[128 * 128];
    int job = blockIdx.x;
    int tid = threadIdx.x;
    bool is_lcs = job < 32;

    if (is_lcs) {
        int pi = job & 15;
        const int* pp = (job >= 16) ? neg : pos;
        int p0 = pp[2 * pi], p1 = pp[2 * pi + 1];
        const float* P = lcs_part + (size_t)job * 16384;
        const float* rA = rn + p0 * 128;
        const float* rB = rn + p1 * 128;
        #pragma unroll 2
        for (int c = 0; c < 16; ++c) {
            int base = (c * 256 + tid) * 4;
            int r = base >> 7, j0 = base & 127;
            float4 v[SL];
            #pragma unroll
            for (int s = 0; s < SL; ++s)
                v[s] = *(const float4*)&P[(size_t)s * SLICE_STRIDE + base];
            float4 sacc = v[0];
            #pragma unroll
            for (int s = 1; s < SL; ++s) {
                sacc.x += v[s].x; sacc.y += v[s].y;
                sacc.z += v[s].z; sacc.w += v[s].w;
            }
            float ra = rA[r];
            float4 rb = *(const float4*)&rB[j0];
            float4 sv;
            sv.x = fmaxf((sacc.x * ra * rb.x - 0.8f) * 5.f, 0.f);
            sv.y = fmaxf((sacc.y * ra * rb.y - 0.8f) * 5.f, 0.f);
            sv.z = fmaxf((sacc.z * ra * rb.z - 0.8f) * 5.f, 0.f);
            sv.w = fmaxf((sacc.w * ra * rb.w - 0.8f) * 5.f, 0.f);
            *(float4*)&Sm[base] = sv;
        }
    } else {
        int fj = job - 32;
        int isneg = fj >= 16;
        int pi = fj & 15;
        const int* pp = isneg ? neg : pos;
        int p0 = pp[2 * pi], p1 = pp[2 * pi + 1];
        const float* Pm = m_part + (size_t)fj * 16384;
        const float* Pg = g_part + (size_t)fj * 16384;
        const float* rAm = rn + 4096 + p0 * 128;
        const float* rBm = rn + (isneg ? 12288 : 4096) + p1 * 128;
        const float* rAg = rn + 8192 + p0 * 128;
        const float* rBg = rn + (isneg ? 16384 : 8192) + p1 * 128;
        #pragma unroll 2
        for (int c = 0; c < 16; ++c) {
            int base = (c * 256 + tid) * 4;
            int r = base >> 7, j0 = base & 127;
            float4 vm[SF], vg[SF];
            #pragma unroll
            for (int s = 0; s < SF; ++s) {
                vm[s] = *(const float4*)&Pm[(size_t)s * SLICE_STRIDE + base];
                vg[s] = *(const float4*)&Pg[(size_t)s * SLICE_STRIDE + base];
            }
            float4 macc = vm[0], gacc = vg[0];
            #pragma unroll
            for (int s = 1; s < SF; ++s) {
                macc.x += vm[s].x; macc.y += vm[s].y;
                macc.z += vm[s].z; macc.w += vm[s].w;
                gacc.x += vg[s].x; gacc.y += vg[s].y;
                gacc.z += vg[s].z; gacc.w += vg[s].w;
            }
            float ram = rAm[r], rag = rAg[r];
            float4 rbm = *(const float4*)&rBm[j0];
            float4 rbg = *(const float4*)&rBg[j0];
            float4 mv, gv;
            mv.x = macc.x * ram * rbm.x; mv.y = macc.y * ram * rbm.y;
            mv.z = macc.z * ram * rbm.z; mv.w = macc.w * ram * rbm.w;
            gv.x = gacc.x * rag * rbg.x; gv.y = gacc.y * rag * rbg.y;
            gv.z = gacc.z * rag * rbg.z; gv.w = gacc.w * rag * rbg.w;
            *(float4*)&Sm[base] = mv;
            *(float4*)&Sg[base] = gv;
        }
    }
    __syncthreads();

    if (tid >= 64) return;
    int l = tid;
    const float* SA = Sm + l * 128;            // row l
    const float* SB = Sm + (64 + l) * 128;     // row 64+l
    float a = 0.f, b = 0.f, ua_prev = 0.f, ub_prev = 0.f;

    if (is_lcs) {
        float sa_buf[8], sb_buf[8];
        #pragma unroll
        for (int p = 0; p < 8; ++p) {
            sa_buf[p] = SA[min(max(p - l, 0), 127)];
            sb_buf[p] = SB[min(max(p - 64 - l, 0), 127)];
        }
        #pragma unroll 8
        for (int t = 0; t < 256; ++t) {
            int slot = t & 7;
            float sa = sa_buf[slot], sb = sb_buf[slot];
            float ua = wave_shr1(a);
            float ub = wave_shr1(b);
            float a63 = rdlane63(a);
            if (l == 0) { ua = 0.f; ub = a63; }
            int ja = t - l, jb = t - 64 - l;
            float newa = (sa > 0.5f) ? (ua_prev + sa) : fmaxf(ua, a);
            float newb = (sb > 0.5f) ? (ub_prev + sb) : fmaxf(ub, b);
            if (ja >= 0 && ja < 128) a = newa;
            if (jb >= 0 && jb < 128) b = newb;
            ua_prev = ua; ub_prev = ub;
            sa_buf[slot] = SA[min(max(t + 8 - l, 0), 127)];
            sb_buf[slot] = SB[min(max(t + 8 - 64 - l, 0), 127)];
        }
        if (l == 63) lres[job] = b;
    } else {
        const float* GA = Sg + l * 128;
        const float* GB = Sg + (64 + l) * 128;
        float mab[8], gab[8], mbb[8], gbb[8];
        #pragma unroll
        for (int p = 0; p < 8; ++p) {
            int ja = min(max(p - l, 0), 127), jb = min(max(p - 64 - l, 0), 127);
            mab[p] = SA[ja]; gab[p] = GA[ja];
            mbb[p] = SB[jb]; gbb[p] = GB[jb];
        }
        #pragma unroll 8
        for (int t = 0; t < 256; ++t) {
            int slot = t & 7;
            float ma = mab[slot], ga = gab[slot], mb = mbb[slot], gb = gbb[slot];
            float ua = wave_shr1(a);
            float ub = wave_shr1(b);
            float a63 = rdlane63(a);
            if (l == 0) { ua = 0.f; ub = a63; }
            int ja = t - l, jb = t - 64 - l;
            float x0 = ua_prev, x1 = ga + ua, x2 = ga + a;
            float mx = fmaxf(x0, fmaxf(x1, x2));
            float e0 = __expf((x0 - mx) * 10.f);
            float e1 = __expf((x1 - mx) * 10.f);
            float e2 = __expf((x2 - mx) * 10.f);
            float newa = ma + mx + 0.1f * __logf(e0 + e1 + e2);
            float y0 = ub_prev, y1 = gb + ub, y2 = gb + b;
            float my = fmaxf(y0, fmaxf(y1, y2));
            float f0 = __expf((y0 - my) * 10.f);
            float f1 = __expf((y1 - my) * 10.f);
            float f2 = __expf((y2 - my) * 10.f);
            float newb = mb + my + 0.1f * __logf(f0 + f1 + f2);
            if (ja >= 0 && ja < 128) a = newa;
            if (jb >= 0 && jb < 128) b = newb;
            ua_prev = ua; ub_prev = ub;
            int jan = min(max(t + 8 - l, 0), 127), jbn = min(max(t + 8 - 64 - l, 0), 127);
            mab[slot] = SA[jan]; gab[slot] = GA[jan];
            mbb[slot] = SB[jbn]; gbb[slot] = GB[jbn];
        }
        if (l == 63) fres[job - 32] = b;
    }
}

// ---------------- final combine (1 block, 64 threads) ----------------
__global__ __launch_bounds__(64) void final_kernel(
        const float* __restrict__ xi, const float* __restrict__ xc,
        const float* __restrict__ xb, const float* __restrict__ vl,
        const float* __restrict__ nfeat, const float* __restrict__ lcs_res,
        const float* __restrict__ fsd_res, const float* __restrict__ acc,
        float* __restrict__ out) {
    int lane = threadIdx.x;
    float part = 0.f;

    if (lane < B_) {
        int b = lane;
        float sv = 0.f;
        for (int j = 0; j < NCLS_; ++j) sv += vl[b * NCLS_ + j];
        float inv_i = 1.f / sv;
        float inv_c = 1.f / (sv + 1.f);
        float si = 0.f, sc = 0.f;
        for (int j = 0; j < NCLS_; ++j) {
            float lab = vl[b * NCLS_ + j];
            if (lab != 0.f) {
                si += logf(xi[b * (NCLS_ + 1) + j] + 1e-45f) * lab * inv_i;
                sc += logf(xc[b * (NCLS_ + 1) + j] + 1e-45f) * lab * inv_c;
            }
        }
        sc += logf(xc[b * (NCLS_ + 1) + NCLS_] + 1e-45f) * inv_c;
        float sb = logf(xb[b * (NCLS_ + 1) + NCLS_] + 1e-45f);
        float cls = -(si + sc + sb) / (float)B_;

        float ni = nfeat[b], nc = nfeat[B_ + b], nb = nfeat[2 * B_ + b];
        float f1 = fmaxf(50.f - ni + nc, 0.f);
        float f2 = fmaxf(50.f - nc + nb, 0.f);
        float fv = f1 + f2 + nb;
        float feat = fv * fv / (float)B_;

        float sgn = (b < NPAIR) ? -1.f : 1.f;
        float lcs = sgn * lcs_res[b] / (float)NPAIR;
        float fsd = sgn * fsd_res[b] / (float)NPAIR;

        part = cls + 5e-5f * feat + 0.1f * (lcs + fsd);
    }
    #pragma unroll
    for (int off = 32; off; off >>= 1) part += __shfl_down(part, off);
    if (lane == 0) {
        float guide = acc[0] / (float)B_;
        float sparse = acc[1] / (float)B_;
        out[0] = part + guide + 2e-4f * sparse;
    }
}

// ---------------- launcher ----------------
extern "C" void kernel_launch(void* const* d_in, const int* in_sizes, int n_in,
                              void* d_out, int out_size, void* d_ws, size_t ws_size,
                              hipStream_t stream) {
    const float* act_inst_cls = (const float*)d_in[0];
    const float* act_cont_cls = (const float*)d_in[1];
    const float* act_back_cls = (const float*)d_in[2];
    const float* vid_label    = (const float*)d_in[3];
    const float* temp_att     = (const float*)d_in[4];
    const float* act_inst_feat= (const float*)d_in[5];
    const float* act_cont_feat= (const float*)d_in[6];
    const float* act_back_feat= (const float*)d_in[7];
    const float* temp_cas     = (const float*)d_in[8];
    const float* lcs_candi    = (const float*)d_in[9];
    const float* fsd_act      = (const float*)d_in[10];
    const float* fsd_bak      = (const float*)d_in[11];
    const int*   pos_pair     = (const int*)d_in[12];
    const int*   neg_pair     = (const int*)d_in[13];

    float* ws = (float*)d_ws;
    float* out = (float*)d_out;

    // fixed layout: SL=8 LCS slices + SF=4 m + SF=4 g slices = 16 * 2MB = 33.6MB
    // (R7 FETCH_SIZE confirmed ws_size >= 36MB branch ran)
    size_t part_floats = (size_t)(SL + 2 * SF) * SLICE_STRIDE;
    float* lcs_part = ws;
    float* m_part   = ws + (size_t)SL * SLICE_STRIDE;
    float* g_part   = m_part + (size_t)SF * SLICE_STRIDE;
    float* rn       = ws + part_floats;
    float* nfeat    = rn + 20480;
    float* lres     = nfeat + 96;
    float* fres     = lres + 32;
    float* acc      = fres + 32;

    hipLaunchKernelGGL(sim_mfma_kernel, dim3(32 * SL + 64 * SF), dim3(256), 0, stream,
                       lcs_candi, fsd_act, fsd_bak, pos_pair, neg_pair,
                       lcs_part, m_part, g_part, acc);

    hipLaunchKernelGGL(norm_guide_kernel, dim3(21600), dim3(64), 0, stream,
                       lcs_candi, fsd_act, fsd_bak,
                       act_inst_feat, act_cont_feat, act_back_feat,
                       temp_att, temp_cas, rn, nfeat, acc);

    hipLaunchKernelGGL(dp_kernel, dim3(64), dim3(256), 0, stream,
                       pos_pair, neg_pair, lcs_part, m_part, g_part, rn,
                       lres, fres);

    hipLaunchKernelGGL(final_kernel, dim3(1), dim3(64), 0, stream,
                       act_inst_cls, act_cont_cls, act_back_cls, vid_label,
                       nfeat, lres, fres, acc, out);
}